// Round 3
// baseline (431.776 us; speedup 1.0000x reference)
//
#include <hip/hip_runtime.h>

// B=8 N=96 H=8 HS=32 NS=256.  One block per (b,i) edge row for the two big
// fused kernels. bf16 MFMA 16x16x32 for all edge-side matmuls.
// v3: LayerNorm fused into EL2 epilogue (x never stored; fp32 regs -> global),
// fixing the bf16-x quantization that broke edge_out precision in v2.

#define DI __device__ __forceinline__

typedef float f32x4 __attribute__((ext_vector_type(4)));
typedef short bf16x8 __attribute__((ext_vector_type(8)));

DI unsigned short f2bf(float f) {
  union { float f; unsigned u; } v; v.f = f;
  return (unsigned short)((v.u + 0x7FFFu + ((v.u >> 16) & 1u)) >> 16);
}
DI float bf2f(unsigned short h) {
  union { unsigned u; float f; } v; v.u = ((unsigned)h) << 16;
  return v.f;
}

#define LDE 264            // padded bf16 row stride (96x[256] tiles)
#define SCALE 0.17677669529663687f   // 1/sqrt(32)

#define MFMA(A, B, C) __builtin_amdgcn_mfma_f32_16x16x32_bf16((A), (B), (C), 0, 0, 0)

// ---------------------------------------------------------------------------
// K0: pack weights into bf16 MFMA B-fragment layout.
// frag[( (kt*NT + nt)*64 + lane )*8 + i] = W[kt*32 + (lane>>4)*8 + i][nt*16 + (lane&15)]
// Regions in fb: WeAll(3 mats, NT=48) | WeeAll(NT=48) | EL1(NT=16) | EL2(NT=16)
// ---------------------------------------------------------------------------
__global__ __launch_bounds__(256)
void prep_frags(const float* __restrict__ We_w, const float* __restrict__ Wee_w,
                const float* __restrict__ EL1_w, const float* __restrict__ EL2_w,
                unsigned short* __restrict__ fb)
{
  const int idx = blockIdx.x * 256 + threadIdx.x;
  if (idx >= 524288) return;
  const float* src; int NT, rel;
  if (idx < 196608)      { src = We_w;  NT = 48; rel = idx; }
  else if (idx < 393216) { src = Wee_w; NT = 48; rel = idx - 196608; }
  else if (idx < 458752) { src = EL1_w; NT = 16; rel = idx - 393216; }
  else                   { src = EL2_w; NT = 16; rel = idx - 458752; }
  const int i = rel & 7, l = (rel >> 3) & 63, t = rel >> 9;
  const int nt = t % NT, kt = t / NT;
  const int k = kt * 32 + ((l >> 4) << 3) + i;
  const int col = nt * 16 + (l & 15);
  float v;
  if (NT == 48) v = src[(col >> 8) * 65536 + k * 256 + (col & 255)];
  else          v = src[k * 256 + col];
  fb[idx] = f2bf(v);
}

// ---------------------------------------------------------------------------
// K1: nQ/nK/nV = node @ Wn_w[q] + Wn_b[q], stored as [B,H,N,HS].
// ---------------------------------------------------------------------------
__global__ __launch_bounds__(256)
void node_qkv(const float* __restrict__ node, const float* __restrict__ Ww,
              const float* __restrict__ Wb, float* __restrict__ nQ,
              float* __restrict__ nK, float* __restrict__ nV)
{
  __shared__ float x[4][256];
  const int t = threadIdx.x, r0 = blockIdx.x * 4;
  #pragma unroll
  for (int rr = 0; rr < 4; ++rr) x[rr][t] = node[(r0 + rr) * 256 + t];
  __syncthreads();
  float a0[4], a1[4], a2[4];
  #pragma unroll
  for (int rr = 0; rr < 4; ++rr) { a0[rr] = Wb[t]; a1[rr] = Wb[256 + t]; a2[rr] = Wb[512 + t]; }
  for (int k = 0; k < 256; ++k) {
    const float w0 = Ww[k * 256 + t], w1 = Ww[65536 + k * 256 + t], w2 = Ww[131072 + k * 256 + t];
    #pragma unroll
    for (int rr = 0; rr < 4; ++rr) {
      const float xv = x[rr][k];
      a0[rr] += xv * w0; a1[rr] += xv * w1; a2[rr] += xv * w2;
    }
  }
  const int h = t >> 5, c = t & 31;
  #pragma unroll
  for (int rr = 0; rr < 4; ++rr) {
    const int row = r0 + rr, b = row / 96, j = row - b * 96;
    const int oi = ((b * 8 + h) * 96 + j) * 32 + c;
    nQ[oi] = a0[rr]; nK[oi] = a1[rr]; nV[oi] = a2[rr];
  }
}

// ---------------------------------------------------------------------------
// K2: fused node attention for one (b,i). Static LDS = 57856 B.
//  Phase A: per 16-row tile, Q and K projections in regs, fold dot -> sc.
//  softmax(sc) -> attn.
//  Phase B: V projection in regs, accumulate attn@V in regs -> attw.
// ---------------------------------------------------------------------------
__global__ __launch_bounds__(256, 2)
void node_attn(const float* __restrict__ edge, const float* __restrict__ We_b,
               const unsigned short* __restrict__ WeF,
               const float* __restrict__ nQ, const float* __restrict__ nK,
               const float* __restrict__ nV, float* __restrict__ attw)
{
  __shared__ unsigned short Elds[96 * LDE];   // 50688 B
  __shared__ float sc[768];                   // 3072 B  (scores -> attn)
  __shared__ float nQp[256];                  // 1024 B
  __shared__ float bias[768];                 // 3072 B

  const int tid = threadIdx.x, lane = tid & 63, wid = tid >> 6;
  const int bi = blockIdx.x, b = bi / 96, i = bi - b * 96;

  nQp[tid] = nQ[((b * 8 + (tid >> 5)) * 96 + i) * 32 + (tid & 31)];
  for (int u = tid; u < 768; u += 256) bias[u] = We_b[u];

  const float* Erow = edge + (size_t)bi * 24576;
  for (int u = tid; u < 96 * 64; u += 256) {
    const int j = u >> 6, g = u & 63;
    const float4 v = *(const float4*)(Erow + j * 256 + g * 4);
    const unsigned lo = (unsigned)f2bf(v.x) | ((unsigned)f2bf(v.y) << 16);
    const unsigned hi = (unsigned)f2bf(v.z) | ((unsigned)f2bf(v.w) << 16);
    *(uint2*)(Elds + j * LDE + g * 4) = make_uint2(lo, hi);
  }
  __syncthreads();

  // ---- Phase A: Q,K projections folded into score dot ----
  for (int mt = 0; mt < 6; ++mt) {
    bf16x8 afr[8];
    const unsigned short* ab = Elds + (mt * 16 + (lane & 15)) * LDE + ((lane >> 4) << 3);
    #pragma unroll
    for (int kt = 0; kt < 8; ++kt) afr[kt] = *(const bf16x8*)(ab + kt * 32);
    #pragma unroll
    for (int pp = 0; pp < 2; ++pp) {
      const int h = wid + (pp << 2);
      f32x4 q0 = {0.f, 0.f, 0.f, 0.f}, q1 = q0, k0 = q0, k1 = q0;
      const unsigned short* wq0 = WeF + ((2 * h) * 64 + lane) * 8;
      const unsigned short* wq1 = WeF + ((2 * h + 1) * 64 + lane) * 8;
      const unsigned short* wk0 = WeF + ((16 + 2 * h) * 64 + lane) * 8;
      const unsigned short* wk1 = WeF + ((17 + 2 * h) * 64 + lane) * 8;
      #pragma unroll
      for (int kt = 0; kt < 8; ++kt) {
        q0 = MFMA(afr[kt], *(const bf16x8*)(wq0 + kt * 24576), q0);
        q1 = MFMA(afr[kt], *(const bf16x8*)(wq1 + kt * 24576), q1);
        k0 = MFMA(afr[kt], *(const bf16x8*)(wk0 + kt * 24576), k0);
        k1 = MFMA(afr[kt], *(const bf16x8*)(wk1 + kt * 24576), k1);
      }
      const int c0 = h * 32 + (lane & 15), c1 = c0 + 16;
      const float qb0 = bias[c0] + nQp[c0], qb1 = bias[c1] + nQp[c1];
      const float kb0 = bias[256 + c0], kb1 = bias[256 + c1];
      float prod[4];
      #pragma unroll
      for (int r = 0; r < 4; ++r) {
        const int j = mt * 16 + ((lane >> 4) << 2) + r;
        const int g = ((b * 8 + h) * 96 + j) * 32;
        const float k0v = k0[r] + kb0 + nK[g + (lane & 15)];
        const float k1v = k1[r] + kb1 + nK[g + 16 + (lane & 15)];
        prod[r] = (q0[r] + qb0) * k0v + (q1[r] + qb1) * k1v;
      }
      #pragma unroll
      for (int m = 1; m < 16; m <<= 1) {
        #pragma unroll
        for (int r = 0; r < 4; ++r) prod[r] += __shfl_xor(prod[r], m, 64);
      }
      if ((lane & 15) == 0) {
        #pragma unroll
        for (int r = 0; r < 4; ++r)
          sc[h * 96 + mt * 16 + ((lane >> 4) << 2) + r] = prod[r];
      }
    }
  }
  __syncthreads();

  // ---- softmax over j per head (32 threads per head, 3 j's per thread) ----
  {
    const int h = tid >> 5, g = tid & 31;
    const float s0 = sc[h * 96 + g] * SCALE;
    const float s1 = sc[h * 96 + g + 32] * SCALE;
    const float s2 = sc[h * 96 + g + 64] * SCALE;
    float mx = fmaxf(s0, fmaxf(s1, s2));
    #pragma unroll
    for (int m = 1; m < 32; m <<= 1) mx = fmaxf(mx, __shfl_xor(mx, m, 64));
    const float e0 = __expf(s0 - mx), e1 = __expf(s1 - mx), e2 = __expf(s2 - mx);
    float sm = e0 + e1 + e2;
    #pragma unroll
    for (int m = 1; m < 32; m <<= 1) sm += __shfl_xor(sm, m, 64);
    const float inv = 1.f / sm;
    sc[h * 96 + g] = e0 * inv; sc[h * 96 + g + 32] = e1 * inv; sc[h * 96 + g + 64] = e2 * inv;
  }
  __syncthreads();

  // ---- Phase B: V projection + attn@V accumulated in registers ----
  {
    float nn[2][2] = {{0.f, 0.f}, {0.f, 0.f}};
    for (int mt = 0; mt < 6; ++mt) {
      bf16x8 afr[8];
      const unsigned short* ab = Elds + (mt * 16 + (lane & 15)) * LDE + ((lane >> 4) << 3);
      #pragma unroll
      for (int kt = 0; kt < 8; ++kt) afr[kt] = *(const bf16x8*)(ab + kt * 32);
      #pragma unroll
      for (int pp = 0; pp < 2; ++pp) {
        const int nt0 = 32 + wid + (pp << 3), nt1 = nt0 + 4;
        f32x4 a0 = {0.f, 0.f, 0.f, 0.f}, a1 = a0;
        const unsigned short* wb0 = WeF + (nt0 * 64 + lane) * 8;
        const unsigned short* wb1 = WeF + (nt1 * 64 + lane) * 8;
        #pragma unroll
        for (int kt = 0; kt < 8; ++kt) {
          a0 = MFMA(afr[kt], *(const bf16x8*)(wb0 + kt * 24576), a0);
          a1 = MFMA(afr[kt], *(const bf16x8*)(wb1 + kt * 24576), a1);
        }
        #pragma unroll
        for (int s = 0; s < 2; ++s) {
          const f32x4 aa = s ? a1 : a0;
          const int col = ((s ? nt1 : nt0) - 32) * 16 + (lane & 15);
          const int h = col >> 5, cc = col & 31;
          const float base = bias[512 + col];
          #pragma unroll
          for (int r = 0; r < 4; ++r) {
            const int j = mt * 16 + ((lane >> 4) << 2) + r;
            const float v = aa[r] + base + nV[((b * 8 + h) * 96 + j) * 32 + cc];
            nn[pp][s] += sc[h * 96 + j] * v;
          }
        }
      }
    }
    #pragma unroll
    for (int pp = 0; pp < 2; ++pp)
      #pragma unroll
      for (int s = 0; s < 2; ++s) {
        nn[pp][s] += __shfl_xor(nn[pp][s], 16, 64);
        nn[pp][s] += __shfl_xor(nn[pp][s], 32, 64);
      }
    if (lane < 16) {
      #pragma unroll
      for (int pp = 0; pp < 2; ++pp)
        #pragma unroll
        for (int s = 0; s < 2; ++s)
          attw[(size_t)bi * 256 + (wid + (pp << 3) + (s << 2)) * 16 + lane] = nn[pp][s];
    }
  }
}

// ---------------------------------------------------------------------------
// K3: node FFN + residual + LayerNorm. 96 blocks x 256 threads, 8 rows each.
// ---------------------------------------------------------------------------
__global__ __launch_bounds__(256)
void node_ffn_ln(const float* __restrict__ attw, const float* __restrict__ node,
                 const float* __restrict__ W1, const float* __restrict__ B1,
                 const float* __restrict__ W2, const float* __restrict__ B2,
                 const float* __restrict__ g, const float* __restrict__ be,
                 float* __restrict__ node_out)
{
  __shared__ float xa[8][256];
  __shared__ float h1[8][256];
  __shared__ float xr[8][256];
  const int t = threadIdx.x, r0 = blockIdx.x * 8;
  #pragma unroll
  for (int rr = 0; rr < 8; ++rr) xa[rr][t] = attw[(r0 + rr) * 256 + t];
  __syncthreads();
  float acc[8];
  #pragma unroll
  for (int rr = 0; rr < 8; ++rr) acc[rr] = B1[t];
  for (int k = 0; k < 256; ++k) {
    const float w = W1[k * 256 + t];
    #pragma unroll
    for (int rr = 0; rr < 8; ++rr) acc[rr] += xa[rr][k] * w;
  }
  #pragma unroll
  for (int rr = 0; rr < 8; ++rr) h1[rr][t] = fmaxf(acc[rr], 0.f);
  __syncthreads();
  #pragma unroll
  for (int rr = 0; rr < 8; ++rr) acc[rr] = B2[t];
  for (int k = 0; k < 256; ++k) {
    const float w = W2[k * 256 + t];
    #pragma unroll
    for (int rr = 0; rr < 8; ++rr) acc[rr] += h1[rr][k] * w;
  }
  #pragma unroll
  for (int rr = 0; rr < 8; ++rr) xr[rr][t] = node[(r0 + rr) * 256 + t] + acc[rr];
  __syncthreads();
  const int wid = t >> 6, lane = t & 63;
  const float4 gv = *(const float4*)(g + (lane << 2));
  const float4 bv = *(const float4*)(be + (lane << 2));
  for (int rr = wid * 2; rr < wid * 2 + 2; ++rr) {
    const float4 xv = *(const float4*)(&xr[rr][lane << 2]);
    float s = xv.x + xv.y + xv.z + xv.w;
    float sq = xv.x * xv.x + xv.y * xv.y + xv.z * xv.z + xv.w * xv.w;
    #pragma unroll
    for (int m = 1; m < 64; m <<= 1) { s += __shfl_xor(s, m, 64); sq += __shfl_xor(sq, m, 64); }
    const float mean = s * (1.f / 256.f);
    const float rs = rsqrtf(sq * (1.f / 256.f) - mean * mean + 1e-5f);
    float4 o;
    o.x = (xv.x - mean) * rs * gv.x + bv.x;
    o.y = (xv.y - mean) * rs * gv.y + bv.y;
    o.z = (xv.z - mean) * rs * gv.z + bv.z;
    o.w = (xv.w - mean) * rs * gv.w + bv.w;
    *(float4*)(node_out + (r0 + rr) * 256 + (lane << 2)) = o;
  }
}

// ---------------------------------------------------------------------------
// K4: n1Q..n2V = node_out @ {Wn1,Wn2} (+bias), stored [B,H,N,HS].
// ---------------------------------------------------------------------------
__global__ __launch_bounds__(256)
void node_proj6(const float* __restrict__ nodeo,
                const float* __restrict__ W1, const float* __restrict__ B1,
                const float* __restrict__ W2, const float* __restrict__ B2,
                float* __restrict__ n1Q, float* __restrict__ n1K, float* __restrict__ n1V,
                float* __restrict__ n2Q, float* __restrict__ n2K, float* __restrict__ n2V)
{
  __shared__ float x[4][256];
  const int t = threadIdx.x, r0 = blockIdx.x * 4;
  #pragma unroll
  for (int rr = 0; rr < 4; ++rr) x[rr][t] = nodeo[(r0 + rr) * 256 + t];
  __syncthreads();
  float a[6][4];
  #pragma unroll
  for (int rr = 0; rr < 4; ++rr) {
    a[0][rr] = B1[t]; a[1][rr] = B1[256 + t]; a[2][rr] = B1[512 + t];
    a[3][rr] = B2[t]; a[4][rr] = B2[256 + t]; a[5][rr] = B2[512 + t];
  }
  for (int k = 0; k < 256; ++k) {
    const float w0 = W1[k * 256 + t], w1 = W1[65536 + k * 256 + t], w2 = W1[131072 + k * 256 + t];
    const float w3 = W2[k * 256 + t], w4 = W2[65536 + k * 256 + t], w5 = W2[131072 + k * 256 + t];
    #pragma unroll
    for (int rr = 0; rr < 4; ++rr) {
      const float xv = x[rr][k];
      a[0][rr] += xv * w0; a[1][rr] += xv * w1; a[2][rr] += xv * w2;
      a[3][rr] += xv * w3; a[4][rr] += xv * w4; a[5][rr] += xv * w5;
    }
  }
  const int h = t >> 5, c = t & 31;
  #pragma unroll
  for (int rr = 0; rr < 4; ++rr) {
    const int row = r0 + rr, b = row / 96, j = row - b * 96;
    const int oi = ((b * 8 + h) * 96 + j) * 32 + c;
    n1Q[oi] = a[0][rr]; n1K[oi] = a[1][rr]; n1V[oi] = a[2][rr];
    n2Q[oi] = a[3][rr]; n2K[oi] = a[4][rr]; n2V[oi] = a[5][rr];
  }
}

// ---------------------------------------------------------------------------
// K5: fused edge update for one (b,i). Static LDS = 64640 B.
//  Phase A: Qe,Ke projections folded into se dot. silu.
//  Phase B: Ve projection, scale by silu, write IN PLACE over E tile.
//  EL1 (in place) -> hidden; EL2 + residual + LayerNorm fused in registers
//  (per-tile cross-wave stats via LDS partials) -> edge_out directly.
// ---------------------------------------------------------------------------
__global__ __launch_bounds__(256, 2)
void edge_update(const float* __restrict__ edge, const float* __restrict__ Wee_b,
                 const unsigned short* __restrict__ WeeF,
                 const unsigned short* __restrict__ EL1F,
                 const unsigned short* __restrict__ EL2F,
                 const float* __restrict__ EL1_b, const float* __restrict__ EL2_b,
                 const float* __restrict__ n1Q, const float* __restrict__ n1K, const float* __restrict__ n1V,
                 const float* __restrict__ n2Q, const float* __restrict__ n2K, const float* __restrict__ n2V,
                 const float* __restrict__ lng, const float* __restrict__ lnb,
                 float* __restrict__ edge_out)
{
  __shared__ unsigned short Elds[96 * LDE];   // 50688 B (E -> attw_e -> hidden)
  __shared__ float se[768];                   // 3072 B
  __shared__ float n1p[768];                  // 3072 B
  __shared__ float bias[768];                 // 3072 B
  __shared__ float b12[512];                  // 2048 B
  __shared__ float lg[256], lb[256];          // 2048 B
  __shared__ float psum[4][16], psq[4][16];   // 512 B
  __shared__ float statm[16], statr[16];      // 128 B

  const int tid = threadIdx.x, lane = tid & 63, wid = tid >> 6;
  const int bi = blockIdx.x, b = bi / 96, i = bi - b * 96;

  for (int u = tid; u < 768; u += 256) {
    bias[u] = Wee_b[u];
    const int q = u >> 8, cn = u & 255, h = cn >> 5, c = cn & 31;
    const float* s = (q == 0) ? n1Q : (q == 1) ? n1K : n1V;
    n1p[u] = s[((b * 8 + h) * 96 + i) * 32 + c];
  }
  for (int u = tid; u < 512; u += 256) b12[u] = (u < 256) ? EL1_b[u] : EL2_b[u - 256];
  lg[tid] = lng[tid]; lb[tid] = lnb[tid];

  const float* Erow = edge + (size_t)bi * 24576;
  for (int u = tid; u < 96 * 64; u += 256) {
    const int j = u >> 6, g = u & 63;
    const float4 v = *(const float4*)(Erow + j * 256 + g * 4);
    const unsigned lo = (unsigned)f2bf(v.x) | ((unsigned)f2bf(v.y) << 16);
    const unsigned hi = (unsigned)f2bf(v.z) | ((unsigned)f2bf(v.w) << 16);
    *(uint2*)(Elds + j * LDE + g * 4) = make_uint2(lo, hi);
  }
  __syncthreads();

  // ---- Phase A: Qe,Ke projections folded into se dot ----
  for (int mt = 0; mt < 6; ++mt) {
    bf16x8 afr[8];
    const unsigned short* ab = Elds + (mt * 16 + (lane & 15)) * LDE + ((lane >> 4) << 3);
    #pragma unroll
    for (int kt = 0; kt < 8; ++kt) afr[kt] = *(const bf16x8*)(ab + kt * 32);
    #pragma unroll
    for (int pp = 0; pp < 2; ++pp) {
      const int h = wid + (pp << 2);
      f32x4 q0 = {0.f, 0.f, 0.f, 0.f}, q1 = q0, k0 = q0, k1 = q0;
      const unsigned short* wq0 = WeeF + ((2 * h) * 64 + lane) * 8;
      const unsigned short* wq1 = WeeF + ((2 * h + 1) * 64 + lane) * 8;
      const unsigned short* wk0 = WeeF + ((16 + 2 * h) * 64 + lane) * 8;
      const unsigned short* wk1 = WeeF + ((17 + 2 * h) * 64 + lane) * 8;
      #pragma unroll
      for (int kt = 0; kt < 8; ++kt) {
        q0 = MFMA(afr[kt], *(const bf16x8*)(wq0 + kt * 24576), q0);
        q1 = MFMA(afr[kt], *(const bf16x8*)(wq1 + kt * 24576), q1);
        k0 = MFMA(afr[kt], *(const bf16x8*)(wk0 + kt * 24576), k0);
        k1 = MFMA(afr[kt], *(const bf16x8*)(wk1 + kt * 24576), k1);
      }
      const int c0 = h * 32 + (lane & 15), c1 = c0 + 16;
      const float qb0 = bias[c0] + n1p[c0], qb1 = bias[c1] + n1p[c1];
      const float kb0 = bias[256 + c0] + n1p[256 + c0];
      const float kb1 = bias[256 + c1] + n1p[256 + c1];
      float prod[4];
      #pragma unroll
      for (int r = 0; r < 4; ++r) {
        const int j = mt * 16 + ((lane >> 4) << 2) + r;
        const int g = ((b * 8 + h) * 96 + j) * 32;
        const float q0v = q0[r] + qb0 + n2Q[g + (lane & 15)];
        const float q1v = q1[r] + qb1 + n2Q[g + 16 + (lane & 15)];
        const float k0v = k0[r] + kb0 + n2K[g + (lane & 15)];
        const float k1v = k1[r] + kb1 + n2K[g + 16 + (lane & 15)];
        prod[r] = q0v * k0v + q1v * k1v;
      }
      #pragma unroll
      for (int m = 1; m < 16; m <<= 1) {
        #pragma unroll
        for (int r = 0; r < 4; ++r) prod[r] += __shfl_xor(prod[r], m, 64);
      }
      if ((lane & 15) == 0) {
        #pragma unroll
        for (int r = 0; r < 4; ++r)
          se[h * 96 + mt * 16 + ((lane >> 4) << 2) + r] = prod[r];
      }
    }
  }
  __syncthreads();

  // ---- silu ----
  for (int u = tid; u < 768; u += 256) {
    const float s = se[u] * SCALE;
    se[u] = s / (1.f + __expf(-s));
  }
  __syncthreads();

  // ---- Phase B: Ve projection, scale by silu, in-place over E tile ----
  for (int mt = 0; mt < 6; ++mt) {
    bf16x8 afr[8];
    const unsigned short* ab = Elds + (mt * 16 + (lane & 15)) * LDE + ((lane >> 4) << 3);
    #pragma unroll
    for (int kt = 0; kt < 8; ++kt) afr[kt] = *(const bf16x8*)(ab + kt * 32);
    float vals[2][2][4];
    int colb[2][2];
    #pragma unroll
    for (int pp = 0; pp < 2; ++pp) {
      const int nt0 = 32 + wid + (pp << 3), nt1 = nt0 + 4;
      f32x4 a0 = {0.f, 0.f, 0.f, 0.f}, a1 = a0;
      const unsigned short* wb0 = WeeF + (nt0 * 64 + lane) * 8;
      const unsigned short* wb1 = WeeF + (nt1 * 64 + lane) * 8;
      #pragma unroll
      for (int kt = 0; kt < 8; ++kt) {
        a0 = MFMA(afr[kt], *(const bf16x8*)(wb0 + kt * 24576), a0);
        a1 = MFMA(afr[kt], *(const bf16x8*)(wb1 + kt * 24576), a1);
      }
      #pragma unroll
      for (int s = 0; s < 2; ++s) {
        const f32x4 aa = s ? a1 : a0;
        const int col = ((s ? nt1 : nt0) - 32) * 16 + (lane & 15);
        const int h = col >> 5, cc = col & 31;
        const float base = bias[512 + col] + n1p[512 + col];
        colb[pp][s] = col;
        #pragma unroll
        for (int r = 0; r < 4; ++r) {
          const int j = mt * 16 + ((lane >> 4) << 2) + r;
          const float v = aa[r] + base + n2V[((b * 8 + h) * 96 + j) * 32 + cc];
          vals[pp][s][r] = se[h * 96 + j] * v;
        }
      }
    }
    __syncthreads();   // all waves done reading E rows of this tile
    #pragma unroll
    for (int pp = 0; pp < 2; ++pp)
      #pragma unroll
      for (int s = 0; s < 2; ++s)
        #pragma unroll
        for (int r = 0; r < 4; ++r) {
          const int j = mt * 16 + ((lane >> 4) << 2) + r;
          Elds[j * LDE + colb[pp][s]] = f2bf(vals[pp][s][r]);
        }
  }
  __syncthreads();

  // ---- EL1 + relu, in place (attw_e -> hidden) ----
  for (int mt = 0; mt < 6; ++mt) {
    bf16x8 afr[8];
    const unsigned short* ab = Elds + (mt * 16 + (lane & 15)) * LDE + ((lane >> 4) << 3);
    #pragma unroll
    for (int kt = 0; kt < 8; ++kt) afr[kt] = *(const bf16x8*)(ab + kt * 32);
    float vals[2][2][4];
    int colb[2][2];
    #pragma unroll
    for (int pp = 0; pp < 2; ++pp) {
      const int nt0 = wid + (pp << 3), nt1 = nt0 + 4;
      f32x4 a0 = {0.f, 0.f, 0.f, 0.f}, a1 = a0;
      const unsigned short* wb0 = EL1F + (nt0 * 64 + lane) * 8;
      const unsigned short* wb1 = EL1F + (nt1 * 64 + lane) * 8;
      #pragma unroll
      for (int kt = 0; kt < 8; ++kt) {
        a0 = MFMA(afr[kt], *(const bf16x8*)(wb0 + kt * 8192), a0);
        a1 = MFMA(afr[kt], *(const bf16x8*)(wb1 + kt * 8192), a1);
      }
      #pragma unroll
      for (int s = 0; s < 2; ++s) {
        const f32x4 aa = s ? a1 : a0;
        const int col = (s ? nt1 : nt0) * 16 + (lane & 15);
        const float bv = b12[col];
        colb[pp][s] = col;
        #pragma unroll
        for (int r = 0; r < 4; ++r) vals[pp][s][r] = fmaxf(aa[r] + bv, 0.f);
      }
    }
    __syncthreads();
    #pragma unroll
    for (int pp = 0; pp < 2; ++pp)
      #pragma unroll
      for (int s = 0; s < 2; ++s)
        #pragma unroll
        for (int r = 0; r < 4; ++r) {
          const int j = mt * 16 + ((lane >> 4) << 2) + r;
          Elds[j * LDE + colb[pp][s]] = f2bf(vals[pp][s][r]);
        }
  }
  __syncthreads();

  // ---- EL2 + residual + LayerNorm fused, fp32 regs -> edge_out ----
  float* orow = edge_out + (size_t)bi * 24576;
  for (int mt = 0; mt < 6; ++mt) {
    bf16x8 afr[8];
    const unsigned short* ab = Elds + (mt * 16 + (lane & 15)) * LDE + ((lane >> 4) << 3);
    #pragma unroll
    for (int kt = 0; kt < 8; ++kt) afr[kt] = *(const bf16x8*)(ab + kt * 32);
    float vals[2][2][4];
    int colb[2][2];
    #pragma unroll
    for (int pp = 0; pp < 2; ++pp) {
      const int nt0 = wid + (pp << 3), nt1 = nt0 + 4;
      f32x4 a0 = {0.f, 0.f, 0.f, 0.f}, a1 = a0;
      const unsigned short* wb0 = EL2F + (nt0 * 64 + lane) * 8;
      const unsigned short* wb1 = EL2F + (nt1 * 64 + lane) * 8;
      #pragma unroll
      for (int kt = 0; kt < 8; ++kt) {
        a0 = MFMA(afr[kt], *(const bf16x8*)(wb0 + kt * 8192), a0);
        a1 = MFMA(afr[kt], *(const bf16x8*)(wb1 + kt * 8192), a1);
      }
      #pragma unroll
      for (int s = 0; s < 2; ++s) {
        const f32x4 aa = s ? a1 : a0;
        const int col = (s ? nt1 : nt0) * 16 + (lane & 15);
        const float bv = b12[256 + col];
        colb[pp][s] = col;
        #pragma unroll
        for (int r = 0; r < 4; ++r) {
          const int j = mt * 16 + ((lane >> 4) << 2) + r;
          vals[pp][s][r] = aa[r] + bv + Erow[j * 256 + col];
        }
      }
    }
    // per-row partial sums (this lane covers 4 cols per row over pp,s)
    #pragma unroll
    for (int r = 0; r < 4; ++r) {
      float s = 0.f, q = 0.f;
      #pragma unroll
      for (int pp = 0; pp < 2; ++pp)
        #pragma unroll
        for (int ss = 0; ss < 2; ++ss) {
          const float v = vals[pp][ss][r];
          s += v; q += v * v;
        }
      #pragma unroll
      for (int m = 1; m < 16; m <<= 1) { s += __shfl_xor(s, m, 64); q += __shfl_xor(q, m, 64); }
      if ((lane & 15) == 0) {
        const int rloc = ((lane >> 4) << 2) + r;
        psum[wid][rloc] = s; psq[wid][rloc] = q;
      }
    }
    __syncthreads();
    if (tid < 16) {
      const float s = psum[0][tid] + psum[1][tid] + psum[2][tid] + psum[3][tid];
      const float q = psq[0][tid] + psq[1][tid] + psq[2][tid] + psq[3][tid];
      const float mean = s * (1.f / 256.f);
      statm[tid] = mean;
      statr[tid] = rsqrtf(q * (1.f / 256.f) - mean * mean + 1e-5f);
    }
    __syncthreads();
    #pragma unroll
    for (int pp = 0; pp < 2; ++pp)
      #pragma unroll
      for (int ss = 0; ss < 2; ++ss) {
        const int col = colb[pp][ss];
        const float gv = lg[col], bvv = lb[col];
        #pragma unroll
        for (int r = 0; r < 4; ++r) {
          const int rloc = ((lane >> 4) << 2) + r;
          const int j = mt * 16 + rloc;
          orow[j * 256 + col] = (vals[pp][ss][r] - statm[rloc]) * statr[rloc] * gv + bvv;
        }
      }
  }
}

// ---------------------------------------------------------------------------
extern "C" void kernel_launch(void* const* d_in, const int* in_sizes, int n_in,
                              void* d_out, int out_size, void* d_ws, size_t ws_size,
                              hipStream_t stream)
{
  (void)in_sizes; (void)n_in; (void)out_size; (void)ws_size;

  const float* node   = (const float*)d_in[0];
  const float* edge   = (const float*)d_in[1];
  const float* Wn_w   = (const float*)d_in[2];
  const float* Wn_b   = (const float*)d_in[3];
  const float* We_w   = (const float*)d_in[4];
  const float* We_b   = (const float*)d_in[5];
  const float* Wn1_w  = (const float*)d_in[6];
  const float* Wn1_b  = (const float*)d_in[7];
  const float* Wn2_w  = (const float*)d_in[8];
  const float* Wn2_b  = (const float*)d_in[9];
  const float* Wee_w  = (const float*)d_in[10];
  const float* Wee_b  = (const float*)d_in[11];
  const float* NL1_w  = (const float*)d_in[12];
  const float* NL1_b  = (const float*)d_in[13];
  const float* NL2_w  = (const float*)d_in[14];
  const float* NL2_b  = (const float*)d_in[15];
  const float* EL1_w  = (const float*)d_in[16];
  const float* EL1_b  = (const float*)d_in[17];
  const float* EL2_w  = (const float*)d_in[18];
  const float* EL2_b  = (const float*)d_in[19];
  const float* NLN1_g = (const float*)d_in[20];
  const float* NLN1_b = (const float*)d_in[21];
  const float* ELN1_g = (const float*)d_in[22];
  const float* ELN1_b = (const float*)d_in[23];

  float* out = (float*)d_out;
  float* node_out = out;               // [8,96,256]
  float* edge_out = out + 196608;      // [8,96,96,256]

  float* wsf = (float*)d_ws;
  float* nQ  = wsf;                float* nK  = wsf + 196608;   float* nV  = wsf + 393216;
  float* n1Q = wsf + 589824;       float* n1K = wsf + 786432;   float* n1V = wsf + 983040;
  float* n2Q = wsf + 1179648;      float* n2K = wsf + 1376256;  float* n2V = wsf + 1572864;
  float* attw = wsf + 1769472;
  unsigned short* fb   = (unsigned short*)(wsf + 1966080);
  unsigned short* WeF  = fb;                 // 196608
  unsigned short* WeeF = fb + 196608;        // 196608
  unsigned short* EL1F = fb + 393216;        // 65536
  unsigned short* EL2F = fb + 458752;        // 65536

  prep_frags<<<2048, 256, 0, stream>>>(We_w, Wee_w, EL1_w, EL2_w, fb);
  node_qkv<<<192, 256, 0, stream>>>(node, Wn_w, Wn_b, nQ, nK, nV);
  node_attn<<<768, 256, 0, stream>>>(edge, We_b, WeF, nQ, nK, nV, attw);
  node_ffn_ln<<<96, 256, 0, stream>>>(attw, node, NL1_w, NL1_b, NL2_w, NL2_b,
                                      NLN1_g, NLN1_b, node_out);
  node_proj6<<<192, 256, 0, stream>>>(node_out, Wn1_w, Wn1_b, Wn2_w, Wn2_b,
                                      n1Q, n1K, n1V, n2Q, n2K, n2V);
  edge_update<<<768, 256, 0, stream>>>(edge, Wee_b, WeeF, EL1F, EL2F,
                                       EL1_b, EL2_b, n1Q, n1K, n1V,
                                       n2Q, n2K, n2V, ELN1_g, ELN1_b, edge_out);
}